// Round 1
// 366.251 us; speedup vs baseline: 1.0072x; 1.0072x over previous
//
#include <hip/hip_runtime.h>
#include <hip/hip_bf16.h>
#include <stdint.h>

// Problem constants (from reference): features 8192x128 f32, prototypes 10101x128 f32,
// path_idx 10000x3 i32, weights [0,1,1]/2 -> out[n,l] = 0.5*(F[n].P[idx1] + F[n].P[idx2])
#define M_DIM      8192
#define K_DIM      128
#define NUM_LEAVES 10000
#define N_PAD      10112   // 79 * 128, zero-padded Q rows
#define NT         79      // N tiles of 128
#define MT         64      // M tiles of 128
#define LDS_STRIDE 136     // 128 + 8 bf16 pad (16B) -> b128 reads land on rotating banks

typedef __attribute__((ext_vector_type(8))) short bf16x8;
typedef __attribute__((ext_vector_type(4))) float f32x4;

static __device__ __forceinline__ unsigned short f2bf(float f) {
    union { float f; uint32_t u; } v; v.f = f;
    uint32_t u = v.u;
    // round-to-nearest-even
    u += 0x7FFFu + ((u >> 16) & 1u);
    return (unsigned short)(u >> 16);
}

// fp32 features -> bf16, one float4 per thread (1048576 elems / 4 = 262144 threads)
__global__ void prep_features(const float* __restrict__ F, unsigned short* __restrict__ Fb) {
    int t = blockIdx.x * blockDim.x + threadIdx.x;
    float4 v = ((const float4*)F)[t];
    ushort4 o;
    o.x = f2bf(v.x); o.y = f2bf(v.y); o.z = f2bf(v.z); o.w = f2bf(v.w);
    ((ushort4*)Fb)[t] = o;
}

// Q[l][k] = 0.5*(P[idx[l,1]][k] + P[idx[l,2]][k]) as bf16; rows >= NUM_LEAVES zeroed.
// One float4-chunk per thread: 10112 rows * 32 chunks = 323584 threads (exact grid).
__global__ void prep_q(const float* __restrict__ P, const int* __restrict__ idx,
                       unsigned short* __restrict__ Qb) {
    int t = blockIdx.x * blockDim.x + threadIdx.x;
    int l = t >> 5;
    int c = (t & 31) << 2;
    ushort4 o;
    if (l < NUM_LEAVES) {
        int i1 = idx[l * 3 + 1];
        int i2 = idx[l * 3 + 2];
        float4 a = *(const float4*)&P[(size_t)i1 * K_DIM + c];
        float4 b = *(const float4*)&P[(size_t)i2 * K_DIM + c];
        o.x = f2bf(0.5f * (a.x + b.x));
        o.y = f2bf(0.5f * (a.y + b.y));
        o.z = f2bf(0.5f * (a.z + b.z));
        o.w = f2bf(0.5f * (a.w + b.w));
    } else {
        o.x = 0; o.y = 0; o.z = 0; o.w = 0;
    }
    *(ushort4*)&Qb[(size_t)l * K_DIM + c] = o;
}

// out = Fb @ Qb^T, 128x128 block tile, full K=128 resident in LDS, 4 waves of 64x64.
// MFMA operands SWAPPED vs v0: acc = mfma(Qfrag, Ffrag) so D's reg dim walks leaf
// columns (contiguous in out) -> one float4 nontemporal store per fragment.
__global__ __launch_bounds__(256, 2) void gemm_fq(
    const unsigned short* __restrict__ Fb,
    const unsigned short* __restrict__ Qb,
    float* __restrict__ out) {
    __shared__ unsigned short As[128 * LDS_STRIDE];
    __shared__ unsigned short Bs[128 * LDS_STRIDE];

    const int bn = blockIdx.x;   // 0..78
    const int bm = blockIdx.y;   // 0..63
    const int tid = threadIdx.x;

    // Stage both 128x128 bf16 tiles (32 KB each): 2048 16B chunks, 8 per thread.
    {
        const uint4* gA = (const uint4*)(Fb + (size_t)bm * 128 * K_DIM);
        const uint4* gB = (const uint4*)(Qb + (size_t)bn * 128 * K_DIM);
#pragma unroll
        for (int i = 0; i < 8; ++i) {
            int c = tid + i * 256;      // chunk id; element offset = c*8, row = c>>4
            int r = c >> 4;
            int c8 = (c & 15) << 3;
            uint4 va = gA[c];
            uint4 vb = gB[c];
            *(uint4*)&As[r * LDS_STRIDE + c8] = va;
            *(uint4*)&Bs[r * LDS_STRIDE + c8] = vb;
        }
    }
    __syncthreads();

    const int lane = tid & 63;
    const int w    = tid >> 6;
    const int wm   = (w >> 1) * 64;
    const int wn   = (w & 1) * 64;
    const int l15  = lane & 15;
    const int quad = lane >> 4;

    f32x4 acc[4][4] = {};

#pragma unroll
    for (int kt = 0; kt < 4; ++kt) {
        const int k0 = kt * 32 + quad * 8;
        bf16x8 af[4], bfr[4];
#pragma unroll
        for (int i = 0; i < 4; ++i) {
            af[i]  = *(const bf16x8*)&As[(wm + i * 16 + l15) * LDS_STRIDE + k0];
            bfr[i] = *(const bf16x8*)&Bs[(wn + i * 16 + l15) * LDS_STRIDE + k0];
        }
        // Swapped operands: A = Q fragment (leaf rows -> D row dim),
        //                   B = F fragment (feature rows -> D col dim).
        // Fragment lane layouts for A and B are identical, so reads are unchanged.
#pragma unroll
        for (int mi = 0; mi < 4; ++mi)
#pragma unroll
            for (int ni = 0; ni < 4; ++ni)
                acc[mi][ni] = __builtin_amdgcn_mfma_f32_16x16x32_bf16(
                    bfr[ni], af[mi], acc[mi][ni], 0, 0, 0);
    }

    // Epilogue with swapped-D layout:
    //   out row  n = bm*128 + wm + mi*16 + (lane&15)      (D col dim)
    //   out col  c = bn*128 + wn + ni*16 + quad*4 + reg   (D row dim -> 4 consecutive)
    // Each fragment is one aligned float4 nontemporal store (c % 4 == 0, 40000 % 16 == 0).
    const int nbase = bm * 128 + wm + l15;
    const int cbase = bn * 128 + wn + quad * 4;
#pragma unroll
    for (int mi = 0; mi < 4; ++mi) {
        float* rowp = out + (size_t)(nbase + mi * 16) * NUM_LEAVES;
#pragma unroll
        for (int ni = 0; ni < 4; ++ni) {
            int c = cbase + ni * 16;
            if (c < NUM_LEAVES) {   // c multiple of 4 and 10000 % 4 == 0 -> whole float4 in/out
                __builtin_nontemporal_store(acc[mi][ni], (f32x4*)(rowp + c));
            }
        }
    }
}

extern "C" void kernel_launch(void* const* d_in, const int* in_sizes, int n_in,
                              void* d_out, int out_size, void* d_ws, size_t ws_size,
                              hipStream_t stream) {
    const float* F  = (const float*)d_in[0];   // 8192*128 f32
    const float* P  = (const float*)d_in[1];   // 10101*128 f32
    const int* idx  = (const int*)d_in[2];     // 10000*3 i32
    float* out      = (float*)d_out;           // 8192*10000 f32

    unsigned short* Fb = (unsigned short*)d_ws;            // 8192*128 bf16 (2 MB)
    unsigned short* Qb = Fb + (size_t)M_DIM * K_DIM;       // 10112*128 bf16 (2.6 MB)

    prep_features<<<(M_DIM * K_DIM / 4) / 256, 256, 0, stream>>>(F, Fb);
    prep_q<<<(N_PAD * 32) / 256, 256, 0, stream>>>(P, idx, Qb);
    gemm_fq<<<dim3(NT, MT), 256, 0, stream>>>(Fb, Qb, out);
}

// Round 2
// 338.492 us; speedup vs baseline: 1.0898x; 1.0820x over previous
//
#include <hip/hip_runtime.h>
#include <hip/hip_bf16.h>
#include <stdint.h>

// Problem constants (from reference): features 8192x128 f32, prototypes 10101x128 f32,
// path_idx 10000x3 i32, weights [0,1,1]/2 -> out[n,l] = 0.5*(F[n].P[idx1] + F[n].P[idx2])
#define M_DIM      8192
#define K_DIM      128
#define NUM_LEAVES 10000
#define N_PAD      10112   // 79 * 128, zero-padded Q rows
#define NT         79      // N tiles of 128
#define MT         64      // M tiles of 128
#define LDS_STRIDE 136     // 128 + 8 bf16 pad (16B) -> b128 reads land on rotating banks
#define T_STRIDE   132     // f32 transpose-staging stride: 132%32=4 -> b128 ops hit
                           // 8 distinct 4-bank groups x 8 lanes = minimum phases

typedef __attribute__((ext_vector_type(8))) short bf16x8;
typedef __attribute__((ext_vector_type(4))) float f32x4;

static __device__ __forceinline__ unsigned short f2bf(float f) {
    union { float f; uint32_t u; } v; v.f = f;
    uint32_t u = v.u;
    // round-to-nearest-even
    u += 0x7FFFu + ((u >> 16) & 1u);
    return (unsigned short)(u >> 16);
}

// fp32 features -> bf16, one float4 per thread (1048576 elems / 4 = 262144 threads)
__global__ void prep_features(const float* __restrict__ F, unsigned short* __restrict__ Fb) {
    int t = blockIdx.x * blockDim.x + threadIdx.x;
    float4 v = ((const float4*)F)[t];
    ushort4 o;
    o.x = f2bf(v.x); o.y = f2bf(v.y); o.z = f2bf(v.z); o.w = f2bf(v.w);
    ((ushort4*)Fb)[t] = o;
}

// Q[l][k] = 0.5*(P[idx[l,1]][k] + P[idx[l,2]][k]) as bf16; rows >= NUM_LEAVES zeroed.
__global__ void prep_q(const float* __restrict__ P, const int* __restrict__ idx,
                       unsigned short* __restrict__ Qb) {
    int t = blockIdx.x * blockDim.x + threadIdx.x;
    int l = t >> 5;
    int c = (t & 31) << 2;
    ushort4 o;
    if (l < NUM_LEAVES) {
        int i1 = idx[l * 3 + 1];
        int i2 = idx[l * 3 + 2];
        float4 a = *(const float4*)&P[(size_t)i1 * K_DIM + c];
        float4 b = *(const float4*)&P[(size_t)i2 * K_DIM + c];
        o.x = f2bf(0.5f * (a.x + b.x));
        o.y = f2bf(0.5f * (a.y + b.y));
        o.z = f2bf(0.5f * (a.z + b.z));
        o.w = f2bf(0.5f * (a.w + b.w));
    } else {
        o.x = 0; o.y = 0; o.z = 0; o.w = 0;
    }
    *(ushort4*)&Qb[(size_t)l * K_DIM + c] = o;
}

// out = Fb @ Qb^T, 128x128 block tile, full K=128 resident in LDS, 4 waves of 64x64.
// Epilogue transposes the f32 tile through LDS so each store instruction emits
// 2 rows x 512 B contiguous (vs 16 rows x 64 B before): 8x fewer, 8x larger segments.
__global__ __launch_bounds__(256, 2) void gemm_fq(
    const unsigned short* __restrict__ Fb,
    const unsigned short* __restrict__ Qb,
    float* __restrict__ out) {
    // 69,632 B shared pool: As/Bs (2 x 128 x 136 bf16) during GEMM,
    // reused as 128 x 132 f32 transpose buffer (67,584 B) in the epilogue.
    __shared__ __align__(16) unsigned char smem[2 * 128 * LDS_STRIDE * 2];
    unsigned short* As = (unsigned short*)smem;
    unsigned short* Bs = As + 128 * LDS_STRIDE;
    float* T = (float*)smem;

    const int bn = blockIdx.x;   // 0..78
    const int bm = blockIdx.y;   // 0..63
    const int tid = threadIdx.x;

    // Stage both 128x128 bf16 tiles (32 KB each): 2048 16B chunks, 8 per thread.
    {
        const uint4* gA = (const uint4*)(Fb + (size_t)bm * 128 * K_DIM);
        const uint4* gB = (const uint4*)(Qb + (size_t)bn * 128 * K_DIM);
#pragma unroll
        for (int i = 0; i < 8; ++i) {
            int c = tid + i * 256;      // chunk id; element offset = c*8, row = c>>4
            int r = c >> 4;
            int c8 = (c & 15) << 3;
            uint4 va = gA[c];
            uint4 vb = gB[c];
            *(uint4*)&As[r * LDS_STRIDE + c8] = va;
            *(uint4*)&Bs[r * LDS_STRIDE + c8] = vb;
        }
    }
    __syncthreads();

    const int lane = tid & 63;
    const int w    = tid >> 6;
    const int wm   = (w >> 1) * 64;
    const int wn   = (w & 1) * 64;
    const int l15  = lane & 15;
    const int quad = lane >> 4;

    f32x4 acc[4][4] = {};

#pragma unroll
    for (int kt = 0; kt < 4; ++kt) {
        const int k0 = kt * 32 + quad * 8;
        bf16x8 af[4], bfr[4];
#pragma unroll
        for (int i = 0; i < 4; ++i) {
            af[i]  = *(const bf16x8*)&As[(wm + i * 16 + l15) * LDS_STRIDE + k0];
            bfr[i] = *(const bf16x8*)&Bs[(wn + i * 16 + l15) * LDS_STRIDE + k0];
        }
        // Swapped operands: D's reg dim walks leaf columns (contiguous in out).
#pragma unroll
        for (int mi = 0; mi < 4; ++mi)
#pragma unroll
            for (int ni = 0; ni < 4; ++ni)
                acc[mi][ni] = __builtin_amdgcn_mfma_f32_16x16x32_bf16(
                    bfr[ni], af[mi], acc[mi][ni], 0, 0, 0);
    }

    // ---- Epilogue: transpose through LDS, then long contiguous stores ----
    __syncthreads();   // all waves done reading As/Bs before overwrite

    // acc[mi][ni] covers out row n_local = wm + mi*16 + l15 (feature dim),
    // cols c_local = wn + quad*4 + ni*16 .. +3 (leaf dim, contiguous).
    {
        const int nbase = wm + l15;
        const int cb    = wn + quad * 4;
#pragma unroll
        for (int mi = 0; mi < 4; ++mi) {
            float* trow = T + (size_t)(nbase + mi * 16) * T_STRIDE;
#pragma unroll
            for (int ni = 0; ni < 4; ++ni) {
                *(f32x4*)&trow[cb + ni * 16] = acc[mi][ni];
            }
        }
    }
    __syncthreads();

    // Each wave stores rows [w*32, w*32+32): 2 rows per instruction,
    // 32 lanes x 16 B = 512 B contiguous per row.
    {
        const int half = lane >> 5;         // 0/1 -> row parity within pair
        const int cx   = (lane & 31) << 2;  // f32 col offset 0..124
        int vcols = NUM_LEAVES - bn * 128;  // valid cols in this tile (16 for bn=78)
        if (vcols > 128) vcols = 128;
        const bool ok = cx < vcols;         // whole float4 valid (10000 % 4 == 0)
        float* gbase = out + (size_t)(bm * 128) * NUM_LEAVES + (size_t)bn * 128 + cx;
        const int r0 = w * 32 + half;
#pragma unroll
        for (int it = 0; it < 16; ++it) {
            const int r = r0 + it * 2;
            f32x4 v = *(const f32x4*)&T[(size_t)r * T_STRIDE + cx];
            if (ok) {
                __builtin_nontemporal_store(v, (f32x4*)(gbase + (size_t)r * NUM_LEAVES));
            }
        }
    }
}

extern "C" void kernel_launch(void* const* d_in, const int* in_sizes, int n_in,
                              void* d_out, int out_size, void* d_ws, size_t ws_size,
                              hipStream_t stream) {
    const float* F  = (const float*)d_in[0];   // 8192*128 f32
    const float* P  = (const float*)d_in[1];   // 10101*128 f32
    const int* idx  = (const int*)d_in[2];     // 10000*3 i32
    float* out      = (float*)d_out;           // 8192*10000 f32

    unsigned short* Fb = (unsigned short*)d_ws;            // 8192*128 bf16 (2 MB)
    unsigned short* Qb = Fb + (size_t)M_DIM * K_DIM;       // 10112*128 bf16 (2.6 MB)

    prep_features<<<(M_DIM * K_DIM / 4) / 256, 256, 0, stream>>>(F, Fb);
    prep_q<<<(N_PAD * 32) / 256, 256, 0, stream>>>(P, idx, Qb);
    gemm_fq<<<dim3(NT, MT), 256, 0, stream>>>(Fb, Qb, out);
}